// Round 7
// baseline (127.654 us; speedup 1.0000x reference)
//
#include <hip/hip_runtime.h>
#include <cmath>

#define NPIX   289          // 17*17
#define NU     10           // unique GLCM offsets (12 slots, 2 dups)
#define NF     70           // 4 stat + 6 hist + 60 glcm
#define NWX    60
#define IMG_W  256
#define IMG_HW 65536
#define NWIN   28800        // 8 * 60 * 60
#define ACC    560          // BATCH * NF
#define WPB    4            // waves (windows) per block
#define NBLK   (NWIN / WPB) // 7200

// unique offsets (dr, dc); flat-shift joff = dr*17 + dc
// o:      0      1      2      3      4      5      6      7      8      9
// dr:     0      1      1      1      0      2      0      2      3      2
// dc:     1      1      0     -1      2      0      3      2      0     -2
// joff:   1     18     17     16      2     34      3     36     51     32
// 1/(2*npairs), npairs = (17-dr)*(17-|dc|)
constexpr float INV2N[NU] = {1.f/544.f, 1.f/512.f, 1.f/544.f, 1.f/512.f, 1.f/510.f,
                             1.f/510.f, 1.f/476.f, 1.f/450.f, 1.f/476.f, 1.f/450.f};

// column-validity masks (depend only on dc). Row overflow needs no mask:
// shifted-B bits beyond bit 288 are zero (ballot tail).
struct CMask { unsigned w[10]; };
constexpr CMask mkcm(int dc) {
    CMask m{};
    for (int t = 0; t < NPIX; ++t) {
        int c = t % 17;
        bool ok = (dc >= 0) ? (c <= 16 - dc) : (c >= -dc);
        if (ok) m.w[t >> 5] |= 1u << (t & 31);
    }
    return m;
}
constexpr CMask c_cm1 = mkcm(1), c_cm2 = mkcm(2), c_cm3 = mkcm(3);
constexpr CMask c_cn1 = mkcm(-1), c_cn2 = mkcm(-2);

// per-idx feature constants: {fi, fj, 1/(1+(fi-fj)^2), 0}
struct alignas(16) FT { float v[49][4]; };
constexpr FT mkft() {
    FT f{};
    for (int idx = 0; idx < 49; ++idx) {
        int fi = idx / 7, fj = idx % 7;
        float d2 = (float)((fi - fj) * (fi - fj));
        f.v[idx][0] = (float)fi;
        f.v[idx][1] = (float)fj;
        f.v[idx][2] = 1.0f / (1.0f + d2);
        f.v[idx][3] = 0.f;
    }
    return f;
}
__constant__ FT c_ft = mkft();

// epilogue gather: u in [0,60) -> index into flat uf[5][10]
struct SrcT { unsigned char s[60]; };
constexpr SrcT mksrc() {
    SrcT t{};
    constexpr int s2u[12] = {0,1,2,3,4,1,5,3,6,7,8,9};
    for (int u = 0; u < 60; ++u) t.s[u] = (unsigned char)((u / 12) * 10 + s2u[u % 12]);
    return t;
}
__constant__ SrcT c_src = mksrc();

__device__ __forceinline__ float wsum(float v){ for(int o=32;o;o>>=1) v += __shfl_xor(v,o,64); return v; }
__device__ __forceinline__ float wmax(float v){ for(int o=32;o;o>>=1) v = fmaxf(v,__shfl_xor(v,o,64)); return v; }
__device__ __forceinline__ float wmin(float v){ for(int o=32;o;o>>=1) v = fminf(v,__shfl_xor(v,o,64)); return v; }

// popcount(A & ((B-bitmap) >> JO)) over W words; B words beyond bitmap are 0.
template<int JO, int W>
__device__ __forceinline__ int cnt_off(const unsigned* A, const unsigned* mb) {
    constexpr int wq = JO >> 5;
    constexpr int r  = JO & 31;
    int acc = 0;
#pragma unroll
    for (int w = 0; w < W; ++w) {
        unsigned sh = __builtin_amdgcn_alignbit(mb[w + wq + 1], mb[w + wq], r);
        acc += __popc(A[w] & sh);
    }
    return acc;
}

__global__ __launch_bounds__(256) void feat_kernel(const float* __restrict__ x,
                                                   float* __restrict__ ptot,
                                                   float* __restrict__ pnz,
                                                   int setmask) {
    __shared__ float s_g[WPB][NU * 49];
    __shared__ float s_uf[WPB][5][NU];
    __shared__ float s_s10[WPB][10];

    const int lane = threadIdx.x & 63;
    const int wid  = threadIdx.x >> 6;
    const int widx = blockIdx.x * WPB + wid;
    const int b    = widx / 3600;
    const int rem  = widx - b * 3600;
    const int wy   = rem / NWX;
    const int wx   = rem - wy * NWX;
    const float* img = x + (size_t)(b * 3 + 1) * IMG_HW + (wy * 4) * IMG_W + wx * 4;

    float* gl  = s_g[wid];
    float (*uf)[NU] = s_uf[wid];
    float* ufl = &s_uf[wid][0][0];
    float* s10 = s_s10[wid];

    // lane -> (a,b) bin pair for the GLCM phase
    const int l49 = (lane < 49) ? lane : 48;
    const int ba  = l49 / 7 + 1;       // 1..7
    const int bb  = l49 - (ba - 1) * 7 + 1;
    const int partner = (bb - 1) * 7 + (ba - 1);   // transpose lane within 49
    // XOR masks: plane ^ xm == (bit set in bin index ? plane : ~plane)
    const unsigned long long xm0a = (ba & 1) ? 0ull : ~0ull;
    const unsigned long long xm1a = (ba & 2) ? 0ull : ~0ull;
    const unsigned long long xm2a = (ba & 4) ? 0ull : ~0ull;
    const unsigned long long xm0b = (bb & 1) ? 0ull : ~0ull;
    const unsigned long long xm1b = (bb & 2) ? 0ull : ~0ull;
    const unsigned long long xm2b = (bb & 4) ? 0ull : ~0ull;

    // ---- pass A: load, threshold, quantize, stats; ballots consumed per-k ----
    float lsum = 0.f, lssq = 0.f, lmax = -1e30f, lmin = 1e30f;
    int n = 0, c1 = 0, c2 = 0, c3 = 0, c4 = 0, c5 = 0, c6 = 0;
    unsigned ma32[10], mb32[10];
#pragma unroll
    for (int k = 0; k < 5; ++k) {
        const int t = lane + k * 64;
        float val;
        if (k < 4) {                       // t in [0,255]: always in-window
            const int r = t / 17;
            float p = img[r * (IMG_W - 17) + t];   // r*256 + c == r*239 + t
            val = (p < 10.f) ? 0.f : p;
        } else {                           // 33-element tail
            val = 0.f;
            if (lane < 33) {
                const int r = t / 17;
                float p = img[r * (IMG_W - 17) + t];
                val = (p < 10.f) ? 0.f : p;
            }
        }
        // quantize: 0 -> 0; [10,255) -> floor(val*0.025+0.8125) in [1,7]
        const int qq = (int)fmaf(val, 0.025f, 0.8125f);
        // stats: raw moments (zeros contribute 0 to sum/ssq)
        lsum += val;
        lssq = fmaf(val, val, lssq);
        lmax = fmaxf(lmax, val);                          // zeros can't win (max>=10)
        lmin = fminf(lmin, (val != 0.f) ? val : 1e30f);
        // bit planes (wave-uniform) -- consumed immediately, not stored
        unsigned long long p0 = __ballot(qq & 1);
        unsigned long long p1 = __ballot(qq & 2);
        unsigned long long p2 = __ballot(qq & 4);
        // scalar-pipe histogram
        n  += __popcll(p0 | p1 | p2);
        c1 += __popcll(p0 & ~p1 & ~p2);
        c2 += __popcll(~p0 & p1 & ~p2);
        c3 += __popcll(p0 & p1 & ~p2);
        c4 += __popcll(~p0 & ~p1 & p2);
        c5 += __popcll(p0 & ~p1 & p2);
        c6 += __popcll(~p0 & p1 & p2);
        // per-lane bin bitmaps (inline VALU: beats a DS round-trip, r6 lesson)
        unsigned long long mA = (p0 ^ xm0a) & (p1 ^ xm1a) & (p2 ^ xm2a);
        unsigned long long mB = (p0 ^ xm0b) & (p1 ^ xm1b) & (p2 ^ xm2b);
        ma32[2*k]   = (unsigned)mA;  ma32[2*k+1] = (unsigned)(mA >> 32);
        mb32[2*k]   = (unsigned)mB;  mb32[2*k+1] = (unsigned)(mB >> 32);
    }

    if (n == 0) return;   // all-zero window contributes nothing (no barriers in this kernel)

    const float fn   = (float)n;
    const float sum  = wsum(lsum);
    const float ssq  = wsum(lssq);
    const float mx   = wmax(lmax);
    const float mn   = wmin(lmin);
    const float mean = sum / fn;
    const float var  = fmaxf(ssq / fn - mean * mean, 0.f);
    const float stdv = sqrtf(var);

    if (lane == 0) {
        s10[0] = mean;
        s10[1] = stdv;
        s10[2] = (mx - mean) / (stdv + 1e-9f);
        s10[3] = (mean - mn) / (stdv + 1e-9f);
        s10[4] = (float)c1 * (1.f / 289.f);
        s10[5] = (float)c2 * (1.f / 289.f);
        s10[6] = (float)c3 * (1.f / 289.f);
        s10[7] = (float)c4 * (1.f / 289.f);
        s10[8] = (float)c5 * (1.f / 289.f);
        s10[9] = (float)c6 * (1.f / 289.f);
    }

    // ---- GLCM counts, grouped by dc (shared column-mask hoisting) ----
    int cnta[NU];
    {
        unsigned A[9];
#pragma unroll
        for (int w = 0; w < 9; ++w) A[w] = ma32[w] & c_cm1.w[w];     // dc=+1
        cnta[0] = cnt_off< 1, 9>(A, mb32);
        cnta[1] = cnt_off<18, 9>(A, mb32);
        // dc=0: no column mask
        cnta[2] = cnt_off<17, 9>(ma32, mb32);
        cnta[5] = cnt_off<34, 8>(ma32, mb32);
        cnta[8] = cnt_off<51, 8>(ma32, mb32);
#pragma unroll
        for (int w = 0; w < 9; ++w) A[w] = ma32[w] & c_cm2.w[w];     // dc=+2
        cnta[4] = cnt_off< 2, 9>(A, mb32);
        cnta[7] = cnt_off<36, 8>(A, mb32);
#pragma unroll
        for (int w = 0; w < 9; ++w) A[w] = ma32[w] & c_cm3.w[w];     // dc=+3
        cnta[6] = cnt_off< 3, 9>(A, mb32);
#pragma unroll
        for (int w = 0; w < 9; ++w) A[w] = ma32[w] & c_cn1.w[w];     // dc=-1
        cnta[3] = cnt_off<16, 9>(A, mb32);
#pragma unroll
        for (int w = 0; w < 8; ++w) A[w] = ma32[w] & c_cn2.w[w];     // dc=-2
        cnta[9] = cnt_off<32, 8>(A, mb32);
    }

    // ---- symmetrize via shuffle, stage g into LDS ----
#pragma unroll
    for (int o = 0; o < NU; ++o) {
        int pc = __shfl(cnta[o], partner, 64);
        float g = (float)(cnta[o] + pc) * INV2N[o];
        if (lane < 49) gl[o * 49 + l49] = g;
    }

    // ---- features: 4 sub-lanes per offset, shfl-reduce ----
    // contrast = 2*(sii - sij) by symmetry; per-idx constants from c_ft table
    const int fo  = lane & 15;   // offset (active fo<10)
    const int sub = lane >> 4;   // 0..3
    float gsum=0.f, entU=0.f, homU=0.f, g2=0.f, siU=0.f, siiU=0.f, sijU=0.f;
    if (fo < NU) {
        for (int idx = sub; idx < 49; idx += 4) {
            float g = gl[fo * 49 + idx];
            const float4 t4 = *(const float4*)(&c_ft.v[idx][0]);
            gsum += g;
            entU = fmaf(g, __log2f(g + 1e-8f), entU);
            homU = fmaf(g, t4.z, homU);
            g2   = fmaf(g, g, g2);
            float gfi = g * t4.x;
            siU  += gfi;
            siiU = fmaf(gfi, t4.x, siiU);
            sijU = fmaf(gfi, t4.y, sijU);
        }
    }
#pragma unroll
    for (int s = 16; s <= 32; s <<= 1) {
        gsum += __shfl_xor(gsum, s, 64);  entU += __shfl_xor(entU, s, 64);
        homU += __shfl_xor(homU, s, 64);  g2   += __shfl_xor(g2,   s, 64);
        siU  += __shfl_xor(siU,  s, 64);  siiU += __shfl_xor(siiU, s, 64);
        sijU += __shfl_xor(sijU, s, 64);
    }
    if (fo < NU && sub == 0) {
        const float invg = 1.f / fmaxf(gsum, 1e-12f);
        const float si  = siU  * invg;
        const float sii = siiU * invg;
        const float sij = sijU * invg;
        const float varg = fmaxf(sii - si * si, 0.f);   // == sdi*sdj (symmetric P)
        const float cov  = sij - si * si;
        uf[0][fo] = 2.f * (siiU - sijU) * invg;
        uf[1][fo] = homU * invg;
        uf[2][fo] = sqrtf(g2) * invg;
        uf[3][fo] = (varg < 1e-15f) ? 1.f : cov / fmaxf(varg, 1e-15f);
        uf[4][fo] = -entU;
    }

    // ---- accumulate into partial sets ----
    const int setbase = (widx & setmask) * ACC;
    const int obase   = b * NF;
    for (int t = lane; t < NF; t += 64) {
        float f = (t < 10) ? s10[t] : ufl[c_src.s[t - 10]];
        if (f != 0.f) {
            atomicAdd(&ptot[setbase + obase + t], f);
            atomicAdd(&pnz[setbase + obase + t], 1.f);
        }
    }
}

__global__ void reduce_kernel(const float* __restrict__ ptot,
                              const float* __restrict__ pnz,
                              float* __restrict__ out, int nset) {
    int t = blockIdx.x * blockDim.x + threadIdx.x;
    if (t >= ACC) return;
    float s = 0.f, nz = 0.f;
    for (int k = 0; k < nset; ++k) {
        s  += ptot[(size_t)k * ACC + t];
        nz += pnz[(size_t)k * ACC + t];
    }
    out[t] = s / (nz + 1e-9f);
}

extern "C" void kernel_launch(void* const* d_in, const int* in_sizes, int n_in,
                              void* d_out, int out_size, void* d_ws, size_t ws_size,
                              hipStream_t stream) {
    (void)in_sizes; (void)n_in; (void)out_size;
    const float* x = (const float*)d_in[0];
    float* out = (float*)d_out;

    const size_t per_set = (size_t)2 * ACC * sizeof(float);   // 4480 B
    int maxs = (ws_size >= per_set) ? (int)(ws_size / per_set) : 1;
    int nset = 1;
    while ((nset * 2) <= maxs && nset < 64) nset <<= 1;

    float* ptot = (float*)d_ws;
    float* pnz  = ptot + (size_t)nset * ACC;

    hipMemsetAsync(d_ws, 0, (size_t)nset * per_set, stream);
    feat_kernel<<<dim3(NBLK), dim3(256), 0, stream>>>(x, ptot, pnz, nset - 1);
    reduce_kernel<<<dim3((ACC + 255) / 256), dim3(256), 0, stream>>>(ptot, pnz, out, nset);
}

// Round 8
// 122.977 us; speedup vs baseline: 1.0380x; 1.0380x over previous
//
#include <hip/hip_runtime.h>
#include <cmath>

#define NPIX   289          // 17*17
#define NU     10           // unique GLCM offsets (12 slots, 2 dups)
#define NF     70           // 4 stat + 6 hist + 60 glcm
#define NWX    60
#define IMG_W  256
#define IMG_HW 65536
#define NWIN   28800        // 8 * 60 * 60
#define ACC    560          // BATCH * NF
#define WPB    4            // waves (windows) per block
#define NBLK   (NWIN / WPB) // 7200

// slot -> unique offset index for the 12 reference offsets
__device__ __constant__ int c_s2u[12] = {0,1,2,3,4,1,5,3,6,7,8,9};

// unique offsets (dr, dc); flat-shift joff = dr*17 + dc
// o:      0      1      2      3      4      5      6      7      8      9
// dr:     0      1      1      1      0      2      0      2      3      2
// dc:     1      1      0     -1      2      0      3      2      0     -2
// joff:   1     18     17     16      2     34      3     36     51     32
// 1/(2*npairs), npairs = (17-dr)*(17-|dc|)
constexpr float INV2N[NU] = {1.f/544.f, 1.f/512.f, 1.f/544.f, 1.f/512.f, 1.f/510.f,
                             1.f/510.f, 1.f/476.f, 1.f/450.f, 1.f/476.f, 1.f/450.f};

// column-validity masks (depend only on dc). Row overflow needs no mask:
// shifted-B bits beyond bit 288 are zero (ballot tail).
struct CMask { unsigned w[10]; };
constexpr CMask mkcm(int dc) {
    CMask m{};
    for (int t = 0; t < NPIX; ++t) {
        int c = t % 17;
        bool ok = (dc >= 0) ? (c <= 16 - dc) : (c >= -dc);
        if (ok) m.w[t >> 5] |= 1u << (t & 31);
    }
    return m;
}
constexpr CMask c_cm1 = mkcm(1), c_cm2 = mkcm(2), c_cm3 = mkcm(3);
constexpr CMask c_cn1 = mkcm(-1), c_cn2 = mkcm(-2);

__device__ __forceinline__ float wsum(float v){ for(int o=32;o;o>>=1) v += __shfl_xor(v,o,64); return v; }
__device__ __forceinline__ float wmax(float v){ for(int o=32;o;o>>=1) v = fmaxf(v,__shfl_xor(v,o,64)); return v; }
__device__ __forceinline__ float wmin(float v){ for(int o=32;o;o>>=1) v = fminf(v,__shfl_xor(v,o,64)); return v; }

// popcount(A & ((B-bitmap) >> JO)) over W words; B words beyond bitmap are 0.
template<int JO, int W>
__device__ __forceinline__ int cnt_off(const unsigned* A, const unsigned* mb) {
    constexpr int wq = JO >> 5;
    constexpr int r  = JO & 31;
    int acc = 0;
#pragma unroll
    for (int w = 0; w < W; ++w) {
        unsigned sh = __builtin_amdgcn_alignbit(mb[w + wq + 1], mb[w + wq], r);
        acc += __popc(A[w] & sh);
    }
    return acc;
}

__global__ __launch_bounds__(256, 8) void feat_kernel(const float* __restrict__ x,
                                                      float* __restrict__ ptot,
                                                      float* __restrict__ pnz,
                                                      int setmask) {
    __shared__ float s_g[WPB][NU * 49];
    __shared__ float s_uf[WPB][5][NU];
    __shared__ float s_s10[WPB][10];

    const int lane = threadIdx.x & 63;
    const int wid  = threadIdx.x >> 6;
    const int widx = blockIdx.x * WPB + wid;
    const int b    = widx / 3600;
    const int rem  = widx - b * 3600;
    const int wy   = rem / NWX;
    const int wx   = rem - wy * NWX;
    const float* img = x + (size_t)(b * 3 + 1) * IMG_HW + (wy * 4) * IMG_W + wx * 4;

    float* gl  = s_g[wid];
    float (*uf)[NU] = s_uf[wid];
    float* s10 = s_s10[wid];

    // lane -> (a,b) bin pair for the GLCM phase
    const int l49 = (lane < 49) ? lane : 48;
    const int ba  = l49 / 7 + 1;       // 1..7
    const int bb  = l49 - (ba - 1) * 7 + 1;
    const int partner = (bb - 1) * 7 + (ba - 1);   // transpose lane within 49
    // XOR masks: plane ^ xm == (bit set in bin index ? plane : ~plane)
    const unsigned long long xm0a = (ba & 1) ? 0ull : ~0ull;
    const unsigned long long xm1a = (ba & 2) ? 0ull : ~0ull;
    const unsigned long long xm2a = (ba & 4) ? 0ull : ~0ull;
    const unsigned long long xm0b = (bb & 1) ? 0ull : ~0ull;
    const unsigned long long xm1b = (bb & 2) ? 0ull : ~0ull;
    const unsigned long long xm2b = (bb & 4) ? 0ull : ~0ull;

    // ---- pass A: load, threshold, quantize, stats; ballots consumed per-k ----
    float lsum = 0.f, lssq = 0.f, lmax = -1e30f, lmin = 1e30f;
    int n = 0, c1 = 0, c2 = 0, c3 = 0, c4 = 0, c5 = 0, c6 = 0;
    unsigned ma32[10], mb32[10];
#pragma unroll
    for (int k = 0; k < 5; ++k) {
        const int t = lane + k * 64;
        float val;
        if (k < 4) {                       // t in [0,255]: always in-window
            const int r = t / 17;
            float p = img[r * (IMG_W - 17) + t];   // r*256 + c == r*239 + t
            val = (p < 10.f) ? 0.f : p;
        } else {                           // 33-element tail
            val = 0.f;
            if (lane < 33) {
                const int r = t / 17;
                float p = img[r * (IMG_W - 17) + t];
                val = (p < 10.f) ? 0.f : p;
            }
        }
        // quantize: 0 -> 0; [10,255) -> floor(val*0.025+0.8125) in [1,7]
        const int qq = (int)fmaf(val, 0.025f, 0.8125f);
        // stats: raw moments (zeros contribute 0 to sum/ssq)
        lsum += val;
        lssq = fmaf(val, val, lssq);
        lmax = fmaxf(lmax, val);                          // zeros can't win (max>=10)
        lmin = fminf(lmin, (val != 0.f) ? val : 1e30f);
        // bit planes (wave-uniform) -- consumed immediately, not stored
        unsigned long long p0 = __ballot(qq & 1);
        unsigned long long p1 = __ballot(qq & 2);
        unsigned long long p2 = __ballot(qq & 4);
        // scalar-pipe histogram
        n  += __popcll(p0 | p1 | p2);
        c1 += __popcll(p0 & ~p1 & ~p2);
        c2 += __popcll(~p0 & p1 & ~p2);
        c3 += __popcll(p0 & p1 & ~p2);
        c4 += __popcll(~p0 & ~p1 & p2);
        c5 += __popcll(p0 & ~p1 & p2);
        c6 += __popcll(~p0 & p1 & p2);
        // per-lane bin bitmaps (inline VALU: beats a DS round-trip, r6 lesson)
        unsigned long long mA = (p0 ^ xm0a) & (p1 ^ xm1a) & (p2 ^ xm2a);
        unsigned long long mB = (p0 ^ xm0b) & (p1 ^ xm1b) & (p2 ^ xm2b);
        ma32[2*k]   = (unsigned)mA;  ma32[2*k+1] = (unsigned)(mA >> 32);
        mb32[2*k]   = (unsigned)mB;  mb32[2*k+1] = (unsigned)(mB >> 32);
    }

    if (n == 0) return;   // all-zero window contributes nothing (no barriers in this kernel)

    const float fn   = (float)n;
    const float sum  = wsum(lsum);
    const float ssq  = wsum(lssq);
    const float mx   = wmax(lmax);
    const float mn   = wmin(lmin);
    const float mean = sum / fn;
    const float var  = fmaxf(ssq / fn - mean * mean, 0.f);
    const float stdv = sqrtf(var);

    if (lane == 0) {
        s10[0] = mean;
        s10[1] = stdv;
        s10[2] = (mx - mean) / (stdv + 1e-9f);
        s10[3] = (mean - mn) / (stdv + 1e-9f);
        s10[4] = (float)c1 * (1.f / 289.f);
        s10[5] = (float)c2 * (1.f / 289.f);
        s10[6] = (float)c3 * (1.f / 289.f);
        s10[7] = (float)c4 * (1.f / 289.f);
        s10[8] = (float)c5 * (1.f / 289.f);
        s10[9] = (float)c6 * (1.f / 289.f);
    }

    // ---- GLCM counts, grouped by dc (shared column-mask hoisting) ----
    int cnta[NU];
    {
        unsigned A[9];
#pragma unroll
        for (int w = 0; w < 9; ++w) A[w] = ma32[w] & c_cm1.w[w];     // dc=+1
        cnta[0] = cnt_off< 1, 9>(A, mb32);
        cnta[1] = cnt_off<18, 9>(A, mb32);
        // dc=0: no column mask
        cnta[2] = cnt_off<17, 9>(ma32, mb32);
        cnta[5] = cnt_off<34, 8>(ma32, mb32);
        cnta[8] = cnt_off<51, 8>(ma32, mb32);
#pragma unroll
        for (int w = 0; w < 9; ++w) A[w] = ma32[w] & c_cm2.w[w];     // dc=+2
        cnta[4] = cnt_off< 2, 9>(A, mb32);
        cnta[7] = cnt_off<36, 8>(A, mb32);
#pragma unroll
        for (int w = 0; w < 9; ++w) A[w] = ma32[w] & c_cm3.w[w];     // dc=+3
        cnta[6] = cnt_off< 3, 9>(A, mb32);
#pragma unroll
        for (int w = 0; w < 9; ++w) A[w] = ma32[w] & c_cn1.w[w];     // dc=-1
        cnta[3] = cnt_off<16, 9>(A, mb32);
#pragma unroll
        for (int w = 0; w < 8; ++w) A[w] = ma32[w] & c_cn2.w[w];     // dc=-2
        cnta[9] = cnt_off<32, 8>(A, mb32);
    }

    // ---- symmetrize via shuffle, stage g into LDS ----
#pragma unroll
    for (int o = 0; o < NU; ++o) {
        int pc = __shfl(cnta[o], partner, 64);
        float g = (float)(cnta[o] + pc) * INV2N[o];
        if (lane < 49) gl[o * 49 + l49] = g;
    }

    // ---- features: 4 sub-lanes per offset, shfl-reduce (inline math, no tables) ----
    // contrast = 2*(sii - sij) by symmetry
    const int fo  = lane & 15;   // offset (active fo<10)
    const int sub = lane >> 4;   // 0..3
    float gsum=0.f, entU=0.f, homU=0.f, g2=0.f, siU=0.f, siiU=0.f, sijU=0.f;
    if (fo < NU) {
        for (int idx = sub; idx < 49; idx += 4) {
            float g = gl[fo * 49 + idx];
            int fi = (idx * 37) >> 8;        // idx/7 for idx<49
            int fj = idx - fi * 7;
            float d  = (float)(fi - fj);
            float d2 = d * d;
            float ffi = (float)fi, ffj = (float)fj;
            gsum += g;
            entU = fmaf(g, __log2f(g + 1e-8f), entU);
            homU = fmaf(g, __builtin_amdgcn_rcpf(1.f + d2), homU);
            g2   = fmaf(g, g, g2);
            float gfi = g * ffi;
            siU  += gfi;
            siiU = fmaf(gfi, ffi, siiU);
            sijU = fmaf(gfi, ffj, sijU);
        }
    }
#pragma unroll
    for (int s = 16; s <= 32; s <<= 1) {
        gsum += __shfl_xor(gsum, s, 64);  entU += __shfl_xor(entU, s, 64);
        homU += __shfl_xor(homU, s, 64);  g2   += __shfl_xor(g2,   s, 64);
        siU  += __shfl_xor(siU,  s, 64);  siiU += __shfl_xor(siiU, s, 64);
        sijU += __shfl_xor(sijU, s, 64);
    }
    if (fo < NU && sub == 0) {
        const float invg = 1.f / fmaxf(gsum, 1e-12f);
        const float si  = siU  * invg;
        const float sii = siiU * invg;
        const float sij = sijU * invg;
        const float varg = fmaxf(sii - si * si, 0.f);   // == sdi*sdj (symmetric P)
        const float cov  = sij - si * si;
        uf[0][fo] = 2.f * (siiU - sijU) * invg;
        uf[1][fo] = homU * invg;
        uf[2][fo] = sqrtf(g2) * invg;
        uf[3][fo] = (varg < 1e-15f) ? 1.f : cov / fmaxf(varg, 1e-15f);
        uf[4][fo] = -entU;
    }

    // ---- accumulate into partial sets ----
    const int setbase = (widx & setmask) * ACC;
    const int obase   = b * NF;
    for (int t = lane; t < NF; t += 64) {
        float f;
        if (t < 10) {
            f = s10[t];
        } else {
            int u    = t - 10;
            int grp  = u / 12;          // 0=contrast 1=homog 2=energy 3=corr 4=entropy
            int slot = u - grp * 12;
            f = uf[grp][c_s2u[slot]];
        }
        if (f != 0.f) {
            atomicAdd(&ptot[setbase + obase + t], f);
            atomicAdd(&pnz[setbase + obase + t], 1.f);
        }
    }
}

__global__ void reduce_kernel(const float* __restrict__ ptot,
                              const float* __restrict__ pnz,
                              float* __restrict__ out, int nset) {
    int t = blockIdx.x * blockDim.x + threadIdx.x;
    if (t >= ACC) return;
    float s = 0.f, nz = 0.f;
    for (int k = 0; k < nset; ++k) {
        s  += ptot[(size_t)k * ACC + t];
        nz += pnz[(size_t)k * ACC + t];
    }
    out[t] = s / (nz + 1e-9f);
}

extern "C" void kernel_launch(void* const* d_in, const int* in_sizes, int n_in,
                              void* d_out, int out_size, void* d_ws, size_t ws_size,
                              hipStream_t stream) {
    (void)in_sizes; (void)n_in; (void)out_size;
    const float* x = (const float*)d_in[0];
    float* out = (float*)d_out;

    const size_t per_set = (size_t)2 * ACC * sizeof(float);   // 4480 B
    int maxs = (ws_size >= per_set) ? (int)(ws_size / per_set) : 1;
    int nset = 1;
    while ((nset * 2) <= maxs && nset < 64) nset <<= 1;

    float* ptot = (float*)d_ws;
    float* pnz  = ptot + (size_t)nset * ACC;

    hipMemsetAsync(d_ws, 0, (size_t)nset * per_set, stream);
    feat_kernel<<<dim3(NBLK), dim3(256), 0, stream>>>(x, ptot, pnz, nset - 1);
    reduce_kernel<<<dim3((ACC + 255) / 256), dim3(256), 0, stream>>>(ptot, pnz, out, nset);
}